// Round 1
// baseline (24299.515 us; speedup 1.0000x reference)
//
#include <hip/hip_runtime.h>
#include <hip/hip_cooperative_groups.h>
#include <cmath>

namespace cg = cooperative_groups;

namespace {
constexpr int kNZ = 300, kNX = 400;
constexpr int kNPML = 32;
constexpr int kNZP = 364, kNXP = 464;       // padded grid
constexpr int kNSTEPS = 200, kNSHOTS = 2;
constexpr int kSRC_Z = 34, kREC_Z = 34;     // NPML + 2
constexpr float kDT = 0.001f;
constexpr float kINV_DX = 100.0f;           // 1/DX, DX = 0.01
constexpr int kNCELL = kNZP * kNXP;         // 168896
constexpr int kNTASK = kNSHOTS * kNCELL;    // 337792
constexpr int kBLOCKS = 512;
constexpr int kTHREADS = 256;
}  // namespace

// One cooperative kernel runs the whole simulation.
// ws layout (floats): [lam2mu | lam | mu | dtr | damp] (5*NCELL, premultiplied
// by DT/DX) then per-shot fields [vx vz sxx szz sxz] (2*5*NCELL), then loss[1].
// Total ~10.1 MB.
__global__ __launch_bounds__(kTHREADS, 2) void fwi_kernel(
    const float* __restrict__ Vp, const float* __restrict__ Vs,
    const float* __restrict__ Den, const float* __restrict__ Stf,
    const int* __restrict__ Shot_ids, float* __restrict__ ws,
    float* __restrict__ out)
{
    cg::grid_group grid = cg::this_grid();

    float* lam2mu = ws;
    float* lam    = ws + kNCELL;
    float* mu     = ws + 2 * kNCELL;
    float* dtr    = ws + 3 * kNCELL;   // DT/(rho*DX)
    float* damp   = ws + 4 * kNCELL;
    float* fld    = ws + 5 * kNCELL;   // [shot][5][NCELL]
    float* lossp  = ws + (5 + kNSHOTS * 5) * kNCELL;

    const int gtid = blockIdx.x * blockDim.x + threadIdx.x;
    const int gstride = gridDim.x * blockDim.x;

    // ---- init: model precompute (edge-padded) + sponge; zero fields ----
    for (int c = gtid; c < kNCELL; c += gstride) {
        const int i = c / kNXP;
        const int j = c - i * kNXP;
        int iz = i - kNPML; iz = iz < 0 ? 0 : (iz > kNZ - 1 ? kNZ - 1 : iz);
        int jx = j - kNPML; jx = jx < 0 ? 0 : (jx > kNX - 1 ? kNX - 1 : jx);
        const float vp  = Vp[iz * kNX + jx];
        const float vs  = Vs[iz * kNX + jx];
        const float rho = Den[iz * kNX + jx];
        const float m = vs * vs * rho * 1e-6f;
        const float l = (vp * vp - 2.0f * vs * vs) * rho * 1e-6f;
        const float sc = kDT * kINV_DX;     // DT/DX folded into moduli
        lam[c]    = l * sc;
        mu[c]     = m * sc;
        lam2mu[c] = (l + 2.0f * m) * sc;
        dtr[c]    = kDT / rho * kINV_DX;
        float dz = fmaxf((float)(kNPML - i), (float)(i - (kNZP - 1 - kNPML)));
        dz = fminf(fmaxf(dz, 0.0f), (float)kNPML) * (1.0f / kNPML);
        float dxx = fmaxf((float)(kNPML - j), (float)(j - (kNXP - 1 - kNPML)));
        dxx = fminf(fmaxf(dxx, 0.0f), (float)kNPML) * (1.0f / kNPML);
        damp[c] = expf(-0.1f * (dz * dz + dxx * dxx));
    }
    for (int c = gtid; c < kNSHOTS * 5 * kNCELL; c += gstride) fld[c] = 0.0f;
    if (gtid == 0) lossp[0] = 0.0f;

    const int id0 = Shot_ids[0];
    const int id1 = Shot_ids[1];
    const int sx0 = kNPML + 20 + id0 * ((kNX - 40) / kNSHOTS);
    const int sx1 = kNPML + 20 + id1 * ((kNX - 40) / kNSHOTS);

    float acc = 0.0f;
    grid.sync();

    for (int t = 0; t < kNSTEPS; ++t) {
        // ---- velocity phase: vx,vz from stresses ----
        for (int task = gtid; task < kNTASK; task += gstride) {
            const int s = (task >= kNCELL) ? 1 : 0;
            const int c = task - s * kNCELL;
            const int i = c / kNXP;
            const int j = c - i * kNXP;
            float* F = fld + s * 5 * kNCELL;
            float* vx = F;
            float* vz = F + kNCELL;
            const float* sxx = F + 2 * kNCELL;
            const float* szz = F + 3 * kNCELL;
            const float* sxz = F + 4 * kNCELL;
            const float sxx_c = sxx[c];
            const float sxx_r = (j < kNXP - 1) ? sxx[c + 1] : 0.0f;
            const float sxz_c = sxz[c];
            const float sxz_u = (i > 0) ? sxz[c - kNXP] : 0.0f;
            const float sxz_l = (j > 0) ? sxz[c - 1] : 0.0f;
            const float szz_c = szz[c];
            const float szz_d = (i < kNZP - 1) ? szz[c + kNXP] : 0.0f;
            const float r = dtr[c];
            const float dmp = damp[c];
            const float nvx = (vx[c] + r * ((sxx_r - sxx_c) + (sxz_c - sxz_u))) * dmp;
            const float nvz = (vz[c] + r * ((sxz_c - sxz_l) + (szz_d - szz_c))) * dmp;
            vx[c] = nvx;
            vz[c] = nvz;
            // record vx at REC_Z row, columns [NPML, NPML+NX)
            if (i == kREC_Z && (unsigned)(j - kNPML) < (unsigned)kNX) acc += nvx * nvx;
        }
        grid.sync();
        // ---- stress phase: sxx,szz,sxz from velocities; source injection ----
        for (int task = gtid; task < kNTASK; task += gstride) {
            const int s = (task >= kNCELL) ? 1 : 0;
            const int c = task - s * kNCELL;
            const int i = c / kNXP;
            const int j = c - i * kNXP;
            float* F = fld + s * 5 * kNCELL;
            const float* vx = F;
            const float* vz = F + kNCELL;
            float* sxx = F + 2 * kNCELL;
            float* szz = F + 3 * kNCELL;
            float* sxz = F + 4 * kNCELL;
            const float vx_c = vx[c];
            const float vx_l = (j > 0) ? vx[c - 1] : 0.0f;
            const float vx_d = (i < kNZP - 1) ? vx[c + kNXP] : 0.0f;
            const float vz_c = vz[c];
            const float vz_u = (i > 0) ? vz[c - kNXP] : 0.0f;
            const float vz_r = (j < kNXP - 1) ? vz[c + 1] : 0.0f;
            const float dvx = vx_c - vx_l;   // dxb(vx) * DX
            const float dvz = vz_c - vz_u;   // dzb(vz) * DX
            const float dmp = damp[c];
            const float l2m = lam2mu[c];
            const float l   = lam[c];
            const float m   = mu[c];
            float nsxx = (sxx[c] + (l2m * dvx + l * dvz)) * dmp;
            float nszz = (szz[c] + (l * dvx + l2m * dvz)) * dmp;
            float nsxz = (sxz[c] + m * ((vx_d - vx_c) + (vz_r - vz_c))) * dmp;
            if (i == kSRC_Z) {
                const int sxp = (s == 0) ? sx0 : sx1;
                if (j == sxp) {
                    const int id = (s == 0) ? id0 : id1;
                    const float sval = Stf[id * kNSTEPS + t] * kDT;
                    nsxx += sval;
                    nszz += sval;
                }
            }
            sxx[c] = nsxx;
            szz[c] = nszz;
            sxz[c] = nsxz;
        }
        grid.sync();
    }

    // ---- loss reduction: 0.5 * sum(rec^2) ----
    if (acc != 0.0f) atomicAdd(lossp, acc);
    grid.sync();
    if (gtid == 0) out[0] = 0.5f * lossp[0];
}

extern "C" void kernel_launch(void* const* d_in, const int* in_sizes, int n_in,
                              void* d_out, int out_size, void* d_ws, size_t ws_size,
                              hipStream_t stream) {
    const float* Vp  = (const float*)d_in[0];
    const float* Vs  = (const float*)d_in[1];
    const float* Den = (const float*)d_in[2];
    const float* Stf = (const float*)d_in[3];
    // d_in[4] = Mask (all-ones; identity in the forward value) -- unused
    const int* Shot_ids = (const int*)d_in[5];
    // d_in[6] = ngpu -- unused
    float* out = (float*)d_out;
    float* ws  = (float*)d_ws;

    void* args[] = {(void*)&Vp, (void*)&Vs, (void*)&Den, (void*)&Stf,
                    (void*)&Shot_ids, (void*)&ws, (void*)&out};
    hipLaunchCooperativeKernel((const void*)fwi_kernel, dim3(kBLOCKS),
                               dim3(kTHREADS), args, 0, stream);
}

// Round 2
// 1484.826 us; speedup vs baseline: 16.3652x; 16.3652x over previous
//
#include <hip/hip_runtime.h>
#include <cmath>

namespace {
constexpr int kNZ = 300, kNX = 400;
constexpr int kNPML = 32;
constexpr int kNZP = 364, kNXP = 464;       // padded grid
constexpr int kNSTEPS = 200, kNSHOTS = 2;
constexpr int kSRC_Z = 34, kREC_Z = 34;     // NPML + 2
constexpr float kDT = 0.001f;
constexpr float kINV_DX = 100.0f;           // 1/DX, DX = 0.01
constexpr int kNCELL = kNZP * kNXP;         // 168896
constexpr int kNTASK = kNSHOTS * kNCELL;    // 337792
}  // namespace

// ws layout (floats):
//   [lam2mu | lam | mu | dtr | damp]               5*NCELL   (DT/DX folded in)
//   fields: buf[2][shot][5][NCELL]                 2*2*5*NCELL
//   loss[1]
// total ~16.9 MB. Ping-pong buffers: step t reads buf[t&1], writes buf[1-(t&1)].

__global__ void fwi_init_kernel(const float* __restrict__ Vp,
                                const float* __restrict__ Vs,
                                const float* __restrict__ Den,
                                float* __restrict__ ws) {
    float* lam2mu = ws;
    float* lam    = ws + kNCELL;
    float* mu     = ws + 2 * kNCELL;
    float* dtr    = ws + 3 * kNCELL;
    float* damp   = ws + 4 * kNCELL;
    float* fld    = ws + 5 * kNCELL;                    // both buffers
    float* lossp  = ws + (5 + 2 * kNSHOTS * 5) * kNCELL;

    const int gtid = blockIdx.x * blockDim.x + threadIdx.x;
    const int gstride = gridDim.x * blockDim.x;
    for (int c = gtid; c < kNCELL; c += gstride) {
        const int i = c / kNXP;
        const int j = c - i * kNXP;
        int iz = i - kNPML; iz = iz < 0 ? 0 : (iz > kNZ - 1 ? kNZ - 1 : iz);
        int jx = j - kNPML; jx = jx < 0 ? 0 : (jx > kNX - 1 ? kNX - 1 : jx);
        const float vp  = Vp[iz * kNX + jx];
        const float vs  = Vs[iz * kNX + jx];
        const float rho = Den[iz * kNX + jx];
        const float m = vs * vs * rho * 1e-6f;
        const float l = (vp * vp - 2.0f * vs * vs) * rho * 1e-6f;
        const float sc = kDT * kINV_DX;
        lam[c]    = l * sc;
        mu[c]     = m * sc;
        lam2mu[c] = (l + 2.0f * m) * sc;
        dtr[c]    = kDT / rho * kINV_DX;
        float dz = fmaxf((float)(kNPML - i), (float)(i - (kNZP - 1 - kNPML)));
        dz = fminf(fmaxf(dz, 0.0f), (float)kNPML) * (1.0f / kNPML);
        float dxx = fmaxf((float)(kNPML - j), (float)(j - (kNXP - 1 - kNPML)));
        dxx = fminf(fmaxf(dxx, 0.0f), (float)kNPML) * (1.0f / kNPML);
        damp[c] = expf(-0.1f * (dz * dz + dxx * dxx));
    }
    for (int c = gtid; c < 2 * kNSHOTS * 5 * kNCELL; c += gstride) fld[c] = 0.0f;
    if (gtid == 0) lossp[0] = 0.0f;
}

__device__ __forceinline__ void vel_update(
    const float* __restrict__ vx, const float* __restrict__ vz,
    const float* __restrict__ sxx, const float* __restrict__ szz,
    const float* __restrict__ sxz, const float* __restrict__ dtr,
    const float* __restrict__ damp, int c, int i, int j,
    float& nvx, float& nvz) {
    const float sxx_c = sxx[c];
    const float sxx_r = (j < kNXP - 1) ? sxx[c + 1] : 0.0f;
    const float sxz_c = sxz[c];
    const float sxz_u = (i > 0) ? sxz[c - kNXP] : 0.0f;
    const float sxz_l = (j > 0) ? sxz[c - 1] : 0.0f;
    const float szz_c = szz[c];
    const float szz_d = (i < kNZP - 1) ? szz[c + kNXP] : 0.0f;
    const float r = dtr[c];
    const float dmp = damp[c];
    nvx = (vx[c] + r * ((sxx_r - sxx_c) + (sxz_c - sxz_u))) * dmp;
    nvz = (vz[c] + r * ((sxz_c - sxz_l) + (szz_d - szz_c))) * dmp;
}

// One full timestep (velocity + stress) fused via redundant velocity
// recompute at halo-1 neighbors. Reads buffer p, writes buffer 1-p.
__global__ __launch_bounds__(256) void fwi_step_kernel(
    float* __restrict__ ws, const float* __restrict__ Stf,
    const int* __restrict__ Shot_ids, int t) {
    const int task = blockIdx.x * blockDim.x + threadIdx.x;

    float* lam2mu = ws;
    float* lam    = ws + kNCELL;
    float* mu     = ws + 2 * kNCELL;
    float* dtr    = ws + 3 * kNCELL;
    float* damp   = ws + 4 * kNCELL;
    float* fld    = ws + 5 * kNCELL;
    float* lossp  = ws + (5 + 2 * kNSHOTS * 5) * kNCELL;

    const int p = t & 1;
    float nvx = 0.0f;
    bool isrec = false;

    if (task < kNTASK) {
        const int s = (task >= kNCELL) ? 1 : 0;
        const int c = task - s * kNCELL;
        const int i = c / kNXP;
        const int j = c - i * kNXP;

        const float* Fc = fld + (p * kNSHOTS + s) * 5 * kNCELL;        // cur
        float*       Fn = fld + ((1 - p) * kNSHOTS + s) * 5 * kNCELL;  // nxt
        const float* vx  = Fc;
        const float* vz  = Fc + kNCELL;
        const float* sxx = Fc + 2 * kNCELL;
        const float* szz = Fc + 3 * kNCELL;
        const float* sxz = Fc + 4 * kNCELL;

        // own velocity
        float nvz;
        vel_update(vx, vz, sxx, szz, sxz, dtr, damp, c, i, j, nvx, nvz);
        Fn[c] = nvx;
        Fn[kNCELL + c] = nvz;

        // redundant neighbor velocities (pad = 0 outside grid)
        float vx_l = 0.0f, vx_d = 0.0f, vz_u = 0.0f, vz_r = 0.0f, tmp;
        if (j > 0)        vel_update(vx, vz, sxx, szz, sxz, dtr, damp, c - 1,    i,     j - 1, vx_l, tmp);
        if (i < kNZP - 1) vel_update(vx, vz, sxx, szz, sxz, dtr, damp, c + kNXP, i + 1, j,     vx_d, tmp);
        if (i > 0)        vel_update(vx, vz, sxx, szz, sxz, dtr, damp, c - kNXP, i - 1, j,     tmp, vz_u);
        if (j < kNXP - 1) vel_update(vx, vz, sxx, szz, sxz, dtr, damp, c + 1,    i,     j + 1, tmp, vz_r);

        // stress update from fresh velocities
        const float dvx = nvx - vx_l;
        const float dvz = nvz - vz_u;
        const float dmp = damp[c];
        const float l2m = lam2mu[c];
        const float l   = lam[c];
        const float m   = mu[c];
        float nsxx = (sxx[c] + (l2m * dvx + l * dvz)) * dmp;
        float nszz = (szz[c] + (l * dvx + l2m * dvz)) * dmp;
        float nsxz = (sxz[c] + m * ((vx_d - nvx) + (vz_r - nvz))) * dmp;

        if (i == kSRC_Z) {
            const int id = Shot_ids[s];
            const int sxp = kNPML + 20 + id * ((kNX - 40) / kNSHOTS);
            if (j == sxp) {
                const float sval = Stf[id * kNSTEPS + t] * kDT;
                nsxx += sval;
                nszz += sval;
            }
        }
        Fn[2 * kNCELL + c] = nsxx;
        Fn[3 * kNCELL + c] = nszz;
        Fn[4 * kNCELL + c] = nsxz;

        isrec = (i == kREC_Z) && ((unsigned)(j - kNPML) < (unsigned)kNX);
    }

    // wave-level reduction of recorder energy, one atomic per wave
    float v = isrec ? nvx * nvx : 0.0f;
    for (int off = 32; off > 0; off >>= 1) v += __shfl_down(v, off, 64);
    if ((threadIdx.x & 63) == 0 && v != 0.0f) atomicAdd(lossp, v);
}

__global__ void fwi_finish_kernel(const float* __restrict__ ws,
                                  float* __restrict__ out) {
    const float* lossp = ws + (5 + 2 * kNSHOTS * 5) * kNCELL;
    out[0] = 0.5f * lossp[0];
}

extern "C" void kernel_launch(void* const* d_in, const int* in_sizes, int n_in,
                              void* d_out, int out_size, void* d_ws, size_t ws_size,
                              hipStream_t stream) {
    const float* Vp  = (const float*)d_in[0];
    const float* Vs  = (const float*)d_in[1];
    const float* Den = (const float*)d_in[2];
    const float* Stf = (const float*)d_in[3];
    // d_in[4] = Mask (all-ones; identity in forward value) -- unused
    const int* Shot_ids = (const int*)d_in[5];
    float* out = (float*)d_out;
    float* ws  = (float*)d_ws;

    fwi_init_kernel<<<512, 256, 0, stream>>>(Vp, Vs, Den, ws);
    const int blocks = (kNTASK + 255) / 256;  // 1320
    for (int t = 0; t < kNSTEPS; ++t) {
        fwi_step_kernel<<<blocks, 256, 0, stream>>>(ws, Stf, Shot_ids, t);
    }
    fwi_finish_kernel<<<1, 1, 0, stream>>>(ws, out);
}